// Round 1
// baseline (175.168 us; speedup 1.0000x reference)
//
#include <hip/hip_runtime.h>

#define N_IN 100000
#define N_OUT 5000
#define N_EDGES 200000
#define NF 4
#define NB 128

// ---------- 1. Transpose x (128 x 100000) -> xT (100000 x 128) ----------
__global__ void transpose_kernel(const float* __restrict__ x, float* __restrict__ xT) {
    __shared__ float tile[32][33];
    int bx = blockIdx.x;  // tile along N_IN (3125 tiles)
    int by = blockIdx.y;  // tile along BATCH (4 tiles)
    int tx = threadIdx.x; // 32
    int ty = threadIdx.y; // 8
    int n = bx * 32 + tx;
#pragma unroll
    for (int i = 0; i < 32; i += 8) {
        tile[ty + i][tx] = x[(size_t)(by * 32 + ty + i) * N_IN + n];
    }
    __syncthreads();
    int ob = by * 32 + tx; // batch index, contiguous across lanes
#pragma unroll
    for (int i = 0; i < 32; i += 8) {
        xT[(size_t)(bx * 32 + ty + i) * NB + ob] = tile[tx][ty + i];
    }
}

// ---------- 2a. Histogram of cols ----------
__global__ void hist_kernel(const int* __restrict__ cols, int* __restrict__ counts) {
    int e = blockIdx.x * 256 + threadIdx.x;
    if (e < N_EDGES) atomicAdd(&counts[cols[e]], 1);
}

// ---------- 2b. Exclusive scan of 5000 counts (single block) ----------
__global__ void scan_kernel(const int* __restrict__ counts, int* __restrict__ offsets,
                            int* __restrict__ cursor) {
    __shared__ int sums[256];
    const int PER = 20; // 256*20 = 5120 >= 5000
    int t = threadIdx.x;
    int base = t * PER;
    int local[PER];
    int s = 0;
#pragma unroll
    for (int i = 0; i < PER; ++i) {
        int idx = base + i;
        int v = (idx < N_OUT) ? counts[idx] : 0;
        local[i] = s; // exclusive prefix within this thread's chunk
        s += v;
    }
    sums[t] = s;
    __syncthreads();
    // Hillis-Steele inclusive scan over 256 thread sums
    for (int off = 1; off < 256; off <<= 1) {
        int v = (t >= off) ? sums[t - off] : 0;
        __syncthreads();
        sums[t] += v;
        __syncthreads();
    }
    int excl = sums[t] - s; // exclusive prefix of this thread's chunk
#pragma unroll
    for (int i = 0; i < PER; ++i) {
        int idx = base + i;
        if (idx < N_OUT) {
            int o = excl + local[i];
            offsets[idx] = o;
            cursor[idx] = o;
        }
    }
    if (t == 255) offsets[N_OUT] = sums[255];
}

// ---------- 2c. Scatter edges into column-sorted CSR arrays ----------
__global__ void scatter_kernel(const int* __restrict__ rows, const int* __restrict__ cols,
                               const float4* __restrict__ w4, int* __restrict__ cursor,
                               int* __restrict__ edge_row, float4* __restrict__ edge_w) {
    int e = blockIdx.x * 256 + threadIdx.x;
    if (e >= N_EDGES) return;
    int c = cols[e];
    int pos = atomicAdd(&cursor[c], 1);
    edge_row[pos] = rows[e];
    edge_w[pos] = w4[e];
}

// ---------- 3. Main: one block per column, lane = batch ----------
__global__ __launch_bounds__(NB) void ld1d_main(const float* __restrict__ xT,
                                                const float4* __restrict__ bias4,
                                                const int* __restrict__ offsets,
                                                const int* __restrict__ edge_row,
                                                const float4* __restrict__ edge_w,
                                                float4* __restrict__ out4) {
    int c = blockIdx.x;
    int b = threadIdx.x;
    int s = offsets[c];
    int e = offsets[c + 1];
    float4 acc = bias4[c];
    for (int k = s; k < e; ++k) {
        int r = edge_row[k];      // wave-uniform
        float4 w = edge_w[k];     // wave-uniform
        float xv = xT[(size_t)r * NB + b]; // coalesced 512B wave read
        acc.x = fmaf(xv, w.x, acc.x);
        acc.y = fmaf(xv, w.y, acc.y);
        acc.z = fmaf(xv, w.z, acc.z);
        acc.w = fmaf(xv, w.w, acc.w);
    }
    acc.x = fmaxf(acc.x, 0.f);
    acc.y = fmaxf(acc.y, 0.f);
    acc.z = fmaxf(acc.z, 0.f);
    acc.w = fmaxf(acc.w, 0.f);
    out4[(size_t)b * N_OUT + c] = acc; // out[b][c][:], 16B per thread
}

extern "C" void kernel_launch(void* const* d_in, const int* in_sizes, int n_in,
                              void* d_out, int out_size, void* d_ws, size_t ws_size,
                              hipStream_t stream) {
    const float* x      = (const float*)d_in[0];
    const float* weight = (const float*)d_in[1];
    const float* bias   = (const float*)d_in[2];
    const int*   rows   = (const int*)d_in[3];
    const int*   cols   = (const int*)d_in[4];

    char* ws = (char*)d_ws;
    // workspace layout (bytes):
    float*  xT       = (float*)(ws + 0);          // 100000*128*4 = 51,200,000
    float4* edge_w   = (float4*)(ws + 51200000);  // 200000*16   =  3,200,000
    int*    edge_row = (int*)(ws + 54400000);     // 200000*4    =    800,000
    int*    counts   = (int*)(ws + 55200000);     // 5000*4
    int*    offsets  = (int*)(ws + 55220000);     // 5001*4
    int*    cursor   = (int*)(ws + 55240004);     // 5000*4  (end: 55,260,004)

    hipMemsetAsync(counts, 0, N_OUT * sizeof(int), stream);

    transpose_kernel<<<dim3(N_IN / 32, NB / 32), dim3(32, 8), 0, stream>>>(x, xT);
    hist_kernel<<<(N_EDGES + 255) / 256, 256, 0, stream>>>(cols, counts);
    scan_kernel<<<1, 256, 0, stream>>>(counts, offsets, cursor);
    scatter_kernel<<<(N_EDGES + 255) / 256, 256, 0, stream>>>(rows, cols, (const float4*)weight,
                                                              cursor, edge_row, edge_w);
    ld1d_main<<<N_OUT, NB, 0, stream>>>(xT, (const float4*)bias, offsets, edge_row, edge_w,
                                        (float4*)d_out);
}

// Round 2
// 138.635 us; speedup vs baseline: 1.2635x; 1.2635x over previous
//
#include <hip/hip_runtime.h>

#define N_IN 100000
#define N_OUT 5000
#define N_EDGES 200000
#define NB 128
#define CAP 128            // padded CSR capacity per column (max bin ~70, 14 sigma)
#define T_TILES 3125       // N_IN / 32 transpose tiles
#define S_BLOCKS 782       // ceil(N_EDGES / 256) scatter blocks

// ---------- fused: transpose x -> xT  AND  scatter edges into padded CSR ----------
__global__ __launch_bounds__(256) void fused_prep(
    const float* __restrict__ x, float* __restrict__ xT,
    const int* __restrict__ rows, const int* __restrict__ cols,
    const float4* __restrict__ w4, int* __restrict__ count,
    int* __restrict__ edge_row_p, float4* __restrict__ edge_w_p) {
    __shared__ float tile[32][129];
    int t = threadIdx.x;
    if (blockIdx.x < T_TILES) {
        // ---- transpose tile: 32 n-values x all 128 batches, float4 both sides ----
        int n0 = blockIdx.x * 32;
        int q = t & 7;        // float4 index along n (0..7)
        int brow = t >> 3;    // 0..31
#pragma unroll
        for (int p = 0; p < 4; ++p) {
            int b = brow + 32 * p;
            float4 v = *(const float4*)(x + (size_t)b * N_IN + n0 + 4 * q);
            tile[4 * q + 0][b] = v.x;
            tile[4 * q + 1][b] = v.y;
            tile[4 * q + 2][b] = v.z;
            tile[4 * q + 3][b] = v.w;
        }
        __syncthreads();
        int s = t & 31;       // float4 index along b (0..31)
        int r = t >> 5;       // 0..7
#pragma unroll
        for (int p = 0; p < 4; ++p) {
            int nl = r + 8 * p;
            float4 w;
            w.x = tile[nl][4 * s + 0];
            w.y = tile[nl][4 * s + 1];
            w.z = tile[nl][4 * s + 2];
            w.w = tile[nl][4 * s + 3];
            *(float4*)(xT + (size_t)(n0 + nl) * NB + 4 * s) = w;
        }
    } else {
        // ---- scatter one edge per thread into padded per-column CSR ----
        int e = (blockIdx.x - T_TILES) * 256 + t;
        if (e < N_EDGES) {
            int c = cols[e];
            int pos = atomicAdd(&count[c], 1);
            if (pos < CAP) {
                edge_row_p[c * CAP + pos] = rows[e];
                edge_w_p[c * CAP + pos] = w4[e];
            }
        }
    }
}

// ---------- main: one block per column, lane = batch ----------
__global__ __launch_bounds__(NB) void ld1d_main(
    const float* __restrict__ xT, const float4* __restrict__ bias4,
    const int* __restrict__ count, const int* __restrict__ edge_row_p,
    const float4* __restrict__ edge_w_p, float4* __restrict__ out4) {
    __shared__ int s_row[CAP];
    __shared__ float4 s_w[CAP];
    int c = blockIdx.x;
    int b = threadIdx.x;
    int cnt = count[c];
    cnt = (cnt < CAP) ? cnt : CAP;
    if (b < cnt) {
        s_row[b] = edge_row_p[c * CAP + b];
        s_w[b] = edge_w_p[c * CAP + b];
    }
    float4 acc = bias4[c];
    __syncthreads();
    int k = 0;
    for (; k + 4 <= cnt; k += 4) {
        int r0 = s_row[k], r1 = s_row[k + 1], r2 = s_row[k + 2], r3 = s_row[k + 3];
        // 4 independent gathers in flight
        float x0 = xT[(size_t)r0 * NB + b];
        float x1 = xT[(size_t)r1 * NB + b];
        float x2 = xT[(size_t)r2 * NB + b];
        float x3 = xT[(size_t)r3 * NB + b];
        float4 w0 = s_w[k], w1 = s_w[k + 1], w2 = s_w[k + 2], w3 = s_w[k + 3];
        acc.x = fmaf(x0, w0.x, acc.x); acc.y = fmaf(x0, w0.y, acc.y);
        acc.z = fmaf(x0, w0.z, acc.z); acc.w = fmaf(x0, w0.w, acc.w);
        acc.x = fmaf(x1, w1.x, acc.x); acc.y = fmaf(x1, w1.y, acc.y);
        acc.z = fmaf(x1, w1.z, acc.z); acc.w = fmaf(x1, w1.w, acc.w);
        acc.x = fmaf(x2, w2.x, acc.x); acc.y = fmaf(x2, w2.y, acc.y);
        acc.z = fmaf(x2, w2.z, acc.z); acc.w = fmaf(x2, w2.w, acc.w);
        acc.x = fmaf(x3, w3.x, acc.x); acc.y = fmaf(x3, w3.y, acc.y);
        acc.z = fmaf(x3, w3.z, acc.z); acc.w = fmaf(x3, w3.w, acc.w);
    }
    for (; k < cnt; ++k) {
        int r = s_row[k];
        float xv = xT[(size_t)r * NB + b];
        float4 w = s_w[k];
        acc.x = fmaf(xv, w.x, acc.x); acc.y = fmaf(xv, w.y, acc.y);
        acc.z = fmaf(xv, w.z, acc.z); acc.w = fmaf(xv, w.w, acc.w);
    }
    acc.x = fmaxf(acc.x, 0.f);
    acc.y = fmaxf(acc.y, 0.f);
    acc.z = fmaxf(acc.z, 0.f);
    acc.w = fmaxf(acc.w, 0.f);
    out4[(size_t)b * N_OUT + c] = acc;
}

extern "C" void kernel_launch(void* const* d_in, const int* in_sizes, int n_in,
                              void* d_out, int out_size, void* d_ws, size_t ws_size,
                              hipStream_t stream) {
    const float* x      = (const float*)d_in[0];
    const float* weight = (const float*)d_in[1];
    const float* bias   = (const float*)d_in[2];
    const int*   rows   = (const int*)d_in[3];
    const int*   cols   = (const int*)d_in[4];

    char* ws = (char*)d_ws;
    // workspace layout (bytes, all 16B-aligned):
    float*  xT         = (float*)(ws + 0);           // 100000*128*4  = 51,200,000
    float4* edge_w_p   = (float4*)(ws + 51200000);   // 5000*128*16   = 10,240,000
    int*    edge_row_p = (int*)(ws + 61440000);      // 5000*128*4    =  2,560,000
    int*    count      = (int*)(ws + 64000000);      // 5000*4        (end 64,020,000)

    hipMemsetAsync(count, 0, N_OUT * sizeof(int), stream);

    fused_prep<<<T_TILES + S_BLOCKS, 256, 0, stream>>>(
        x, xT, rows, cols, (const float4*)weight, count, edge_row_p, edge_w_p);

    ld1d_main<<<N_OUT, NB, 0, stream>>>(xT, (const float4*)bias, count,
                                        edge_row_p, edge_w_p, (float4*)d_out);
}